// Round 8
// baseline (604.434 us; speedup 1.0000x reference)
//
#include <hip/hip_runtime.h>
#include <stdint.h>
#include <math.h>

#define NTOK  2048
#define HDIM  1024
#define FDIM  768
#define NEXP  32
#define TOPK  8
#define CAP   1024
#define CVT_GRID 4096

typedef __attribute__((ext_vector_type(8))) short short8;
typedef __attribute__((ext_vector_type(4))) float f32x4;

__device__ __forceinline__ short f2bf(float f) {
  union { float f; uint32_t u; } c; c.f = f;
  uint32_t u = c.u;
  u += 0x7fffu + ((u >> 16) & 1u);   // RNE
  return (short)(u >> 16);
}

__device__ __forceinline__ short8 pack8(float4 a, float4 b) {
  short8 r;
  r[0] = f2bf(a.x); r[1] = f2bf(a.y); r[2] = f2bf(a.z); r[3] = f2bf(a.w);
  r[4] = f2bf(b.x); r[5] = f2bf(b.y); r[6] = f2bf(b.z); r[7] = f2bf(b.w);
  return r;
}

// async global->LDS, 16B per lane; LDS dest must be wave-uniform (HW adds lane*16B)
__device__ __forceinline__ void gload16(const short* g, short* l) {
  __builtin_amdgcn_global_load_lds(
      (__attribute__((address_space(1))) uint32_t*)g,
      (__attribute__((address_space(3))) uint32_t*)l, 16, 0, 0);
}

// ---------------- weight pre-convert fp32 -> bf16 (batched-MLP streaming) ----------------
// grid MUST be CVT_GRID x 256: 1,048,576 threads; gup = 6 granules/thread, dwn = 3 (exact).
// All loads issued before any store -> 12 (resp. 6) outstanding float4 loads per thread.
__global__ __launch_bounds__(256) void cvt_kern(
    const float* __restrict__ gup, const float* __restrict__ dwn,
    short* __restrict__ gupb, short* __restrict__ dwnb) {
  const size_t tid = (size_t)blockIdx.x * 256 + threadIdx.x;
  const size_t STRIDE = (size_t)CVT_GRID * 256;   // 1,048,576

  float4 a[6], b[6];
#pragma unroll
  for (int it = 0; it < 6; ++it) {
    const size_t i = tid + (size_t)it * STRIDE;
    a[it] = *(const float4*)(gup + i * 8);
    b[it] = *(const float4*)(gup + i * 8 + 4);
  }
#pragma unroll
  for (int it = 0; it < 6; ++it) {
    const size_t i = tid + (size_t)it * STRIDE;
    *(short8*)(gupb + i * 8) = pack8(a[it], b[it]);
  }

  float4 c[3], d[3];
#pragma unroll
  for (int it = 0; it < 3; ++it) {
    const size_t i = tid + (size_t)it * STRIDE;
    c[it] = *(const float4*)(dwn + i * 8);
    d[it] = *(const float4*)(dwn + i * 8 + 4);
  }
#pragma unroll
  for (int it = 0; it < 3; ++it) {
    const size_t i = tid + (size_t)it * STRIDE;
    *(short8*)(dwnb + i * 8) = pack8(c[it], d[it]);
  }
}

// ---------------- router: logits (fp32), top-8, renorm weights, scatter, x->bf16 ----------------
__global__ __launch_bounds__(256) void router_kern(
    const float* __restrict__ x, const float* __restrict__ gw,
    int* __restrict__ cnt, int* __restrict__ slot_tok,
    float* __restrict__ slot_w, short* __restrict__ xb) {
  const int n0 = blockIdx.x * 8;      // 8 tokens per block, grid = 256
  const int t  = threadIdx.x;
  __shared__ float ls[8][32];

  const int e = t >> 3;
  const int j = t & 7;
  float acc[8];
#pragma unroll
  for (int i = 0; i < 8; ++i) acc[i] = 0.f;
  const float* gwe = gw + (size_t)e * HDIM;
  for (int i = 0; i < 128; ++i) {
    const int k = j + 8 * i;
    const float gv = gwe[k];
#pragma unroll
    for (int tok = 0; tok < 8; ++tok)
      acc[tok] += gv * x[(size_t)(n0 + tok) * HDIM + k];
  }
#pragma unroll
  for (int tok = 0; tok < 8; ++tok) {
    float v = acc[tok];
    v += __shfl_xor(v, 1); v += __shfl_xor(v, 2); v += __shfl_xor(v, 4);
    if (j == 0) ls[tok][e] = v;
  }
  __syncthreads();

  if (t < 8) {
    const int n = n0 + t;
    float lv[32];
#pragma unroll
    for (int i = 0; i < 32; ++i) lv[i] = ls[t][i];
    int   idx[TOPK];
    float val[TOPK];
    for (int kk = 0; kk < TOPK; ++kk) {
      float best = -INFINITY; int bi = 0;
      for (int i = 0; i < 32; ++i)
        if (lv[i] > best) { best = lv[i]; bi = i; }   // strict > : first-index tie-break
      val[kk] = best; idx[kk] = bi; lv[bi] = -INFINITY;
    }
    const float m = val[0];
    float w[TOPK]; float wsum = 0.f;
    for (int kk = 0; kk < TOPK; ++kk) { w[kk] = __expf(val[kk] - m); wsum += w[kk]; }
    const float inv = 1.f / wsum;
    for (int kk = 0; kk < TOPK; ++kk) {
      const int ee = idx[kk];
      const int pos = atomicAdd(&cnt[ee], 1);
      if (pos < CAP) {
        slot_tok[ee * CAP + pos] = n * TOPK + kk;
        slot_w[ee * CAP + pos]   = w[kk] * inv;
      }
    }
  }

  const size_t base = (size_t)n0 * HDIM;
  for (int i = t; i < 8 * HDIM; i += 256)
    xb[base + i] = f2bf(x[base + i]);
}

// ---------------- GEMM1: h = silu(x@Wg^T)*(x@Wu^T); 128m x 64f; 2-phase dbuf; XCD-affinity ----------------
// 1-D grid 3072. linear_id % 8 == e % 8  -> all 96 blocks of expert e land on XCD e%8; the
// concurrent window per XCD (~32 CU x 3 blocks) is one expert, so its 3MB B-panel is L2-resident.
__global__ __launch_bounds__(256) void gemm1_kern(
    const short* __restrict__ xb, const short* __restrict__ gupb,
    const int* __restrict__ cnt, const int* __restrict__ slot_tok,
    short* __restrict__ hbuf) {
  const int id  = blockIdx.x;
  const int xcd = id & 7;
  const int idx = id >> 3;            // 0..383
  const int e   = xcd + 8 * (idx / 96);
  const int w96 = idx % 96;
  const int f0  = (w96 % 12) * 64;
  const int r0  = (w96 / 12) * 128;

  const int mcnt = min(cnt[e], CAP);
  if (r0 >= mcnt) return;

  __shared__ short As[2][128 * 32];   // 2 x 8 KB
  __shared__ short Bg[2][64 * 32];    // 2 x 4 KB
  __shared__ short Bu[2][64 * 32];    // 2 x 4 KB  -> 32 KB total

  const int t = threadIdx.x;
  const int wave = t >> 6, lane = t & 63;

  // A staging: 2 granules/thread over [128 rows][4 segs]; per-lane gathered source
  const int la0 = wave * 128 + lane;
  const int la1 = la0 + 64;
  const int arow0 = la0 >> 2, aseg0 = la0 & 3;
  const int arow1 = la1 >> 2, aseg1 = la1 & 3;
  int tok0 = 0, tok1 = 0;
  if (r0 + arow0 < mcnt) tok0 = slot_tok[e * CAP + r0 + arow0] >> 3;
  if (r0 + arow1 < mcnt) tok1 = slot_tok[e * CAP + r0 + arow1] >> 3;
  const short* aSrc0 = xb + (size_t)tok0 * HDIM + aseg0 * 8;
  const short* aSrc1 = xb + (size_t)tok1 * HDIM + aseg1 * 8;

  // B staging: 1 granule/thread per operand over [64 rows][4 segs]
  const int brow = t >> 2, bseg = t & 3;
  const short* gSrc = gupb + ((size_t)e * 1536 + f0 + brow) * HDIM + bseg * 8;
  const short* uSrc = gupb + ((size_t)e * 1536 + 768 + f0 + brow) * HDIM + bseg * 8;

  const int wm = (wave & 1) * 64, wf = (wave >> 1) * 32;
  const int lrow = lane & 15, lk = (lane >> 4) * 8;

  f32x4 accg[4][2], accu[4][2];
#pragma unroll
  for (int a = 0; a < 4; ++a)
#pragma unroll
    for (int b = 0; b < 2; ++b) {
      accg[a][b] = (f32x4){0.f, 0.f, 0.f, 0.f};
      accu[a][b] = (f32x4){0.f, 0.f, 0.f, 0.f};
    }

  auto STAGE = [&](int b, int kb) {
    gload16(aSrc0 + kb, &As[b][wave * 1024]);
    gload16(aSrc1 + kb, &As[b][wave * 1024 + 512]);
    gload16(gSrc + kb,  &Bg[b][wave * 512]);
    gload16(uSrc + kb,  &Bu[b][wave * 512]);
  };

  auto COMPUTE = [&](int b) {
    short8 af[4], bg[2], bu[2];
#pragma unroll
    for (int mt = 0; mt < 4; ++mt)
      af[mt] = *(const short8*)&As[b][(wm + mt * 16 + lrow) * 32 + lk];
#pragma unroll
    for (int nt = 0; nt < 2; ++nt) {
      bg[nt] = *(const short8*)&Bg[b][(wf + nt * 16 + lrow) * 32 + lk];
      bu[nt] = *(const short8*)&Bu[b][(wf + nt * 16 + lrow) * 32 + lk];
    }
#pragma unroll
    for (int mt = 0; mt < 4; ++mt)
#pragma unroll
      for (int nt = 0; nt < 2; ++nt) {
        accg[mt][nt] = __builtin_amdgcn_mfma_f32_16x16x32_bf16(af[mt], bg[nt], accg[mt][nt], 0, 0, 0);
        accu[mt][nt] = __builtin_amdgcn_mfma_f32_16x16x32_bf16(af[mt], bu[nt], accu[mt][nt], 0, 0, 0);
      }
  };

  STAGE(0, 0);
  __syncthreads();
  int cur = 0;
  for (int kb = 32; kb < HDIM; kb += 32) {
    STAGE(cur ^ 1, kb);
    COMPUTE(cur);
    __syncthreads();
    cur ^= 1;
  }
  COMPUTE(cur);

  // epilogue: silu(g)*u -> bf16 h[e][pos][f]   (mapping HW-verified rounds 0-3,6,7)
#pragma unroll
  for (int mt = 0; mt < 4; ++mt)
#pragma unroll
    for (int rr = 0; rr < 4; ++rr) {
      const int pos = r0 + wm + mt * 16 + (lane >> 4) * 4 + rr;
      if (pos < mcnt) {
#pragma unroll
        for (int nt = 0; nt < 2; ++nt) {
          const float g = accg[mt][nt][rr];
          const float u = accu[mt][nt][rr];
          const float hv = (g / (1.f + __expf(-g))) * u;
          hbuf[((size_t)e * CAP + pos) * FDIM + f0 + wf + nt * 16 + (lane & 15)] = f2bf(hv);
        }
      }
    }
}

// ---------------- GEMM2: slot_out[s] = w_s * (h @ Wd^T); 128x128; 2-phase dbuf; XCD-affinity ----------------
// 1-D grid 2048: linear_id % 8 == e % 8; 64 blocks/expert; 1.5MB dwn-panel L2-resident per XCD window.
__global__ __launch_bounds__(256) void gemm2_kern(
    const short* __restrict__ hbuf, const short* __restrict__ dwnb,
    const int* __restrict__ cnt, const int* __restrict__ slot_tok,
    const float* __restrict__ slot_w, float* __restrict__ slot_out) {
  const int id  = blockIdx.x;
  const int xcd = id & 7;
  const int idx = id >> 3;            // 0..255
  const int e   = xcd + 8 * (idx >> 6);
  const int w64 = idx & 63;
  const int n0  = (w64 & 7) * 128;
  const int r0  = (w64 >> 3) * 128;

  const int mcnt = min(cnt[e], CAP);
  if (r0 >= mcnt) return;

  __shared__ short As[2][128 * 32];   // 2 x 8 KB
  __shared__ short Bs[2][128 * 32];   // 2 x 8 KB -> 32 KB total

  const int t = threadIdx.x;
  const int wave = t >> 6, lane = t & 63;

  const int l0 = wave * 128 + lane;
  const int l1 = l0 + 64;
  const int ar0 = l0 >> 2, as0 = l0 & 3;
  const int ar1 = l1 >> 2, as1 = l1 & 3;
  const short* aSrc0 = hbuf + ((size_t)e * CAP + r0 + ar0) * FDIM + as0 * 8;
  const short* aSrc1 = hbuf + ((size_t)e * CAP + r0 + ar1) * FDIM + as1 * 8;
  const short* bSrc0 = dwnb + ((size_t)e * HDIM + n0 + ar0) * FDIM + as0 * 8;
  const short* bSrc1 = dwnb + ((size_t)e * HDIM + n0 + ar1) * FDIM + as1 * 8;

  const int wm = (wave & 1) * 64, wn = (wave >> 1) * 64;
  const int lrow = lane & 15, lk = (lane >> 4) * 8;

  f32x4 acc[4][4];
#pragma unroll
  for (int a = 0; a < 4; ++a)
#pragma unroll
    for (int b = 0; b < 4; ++b) acc[a][b] = (f32x4){0.f, 0.f, 0.f, 0.f};

  auto STAGE = [&](int b, int kb) {
    gload16(aSrc0 + kb, &As[b][wave * 1024]);
    gload16(aSrc1 + kb, &As[b][wave * 1024 + 512]);
    gload16(bSrc0 + kb, &Bs[b][wave * 1024]);
    gload16(bSrc1 + kb, &Bs[b][wave * 1024 + 512]);
  };

  auto COMPUTE = [&](int b) {
    short8 af[4], bf[4];
#pragma unroll
    for (int i = 0; i < 4; ++i) {
      af[i] = *(const short8*)&As[b][(wm + i * 16 + lrow) * 32 + lk];
      bf[i] = *(const short8*)&Bs[b][(wn + i * 16 + lrow) * 32 + lk];
    }
#pragma unroll
    for (int mt = 0; mt < 4; ++mt)
#pragma unroll
      for (int nt = 0; nt < 4; ++nt)
        acc[mt][nt] = __builtin_amdgcn_mfma_f32_16x16x32_bf16(af[mt], bf[nt], acc[mt][nt], 0, 0, 0);
  };

  STAGE(0, 0);
  __syncthreads();
  int cur = 0;
  for (int kb = 32; kb < FDIM; kb += 32) {
    STAGE(cur ^ 1, kb);
    COMPUTE(cur);
    __syncthreads();
    cur ^= 1;
  }
  COMPUTE(cur);

  // epilogue: weighted write to slot_out (mapping HW-verified rounds 0-3,6,7)
#pragma unroll
  for (int mt = 0; mt < 4; ++mt)
#pragma unroll
    for (int rr = 0; rr < 4; ++rr) {
      const int pos = r0 + wm + mt * 16 + (lane >> 4) * 4 + rr;
      if (pos < mcnt) {
        const int s = slot_tok[e * CAP + pos];
        const float w = slot_w[e * CAP + pos];
#pragma unroll
        for (int nt = 0; nt < 4; ++nt)
          slot_out[(size_t)s * HDIM + n0 + wn + nt * 16 + (lane & 15)] = w * acc[mt][nt][rr];
      }
    }
}

// ---------------- gather: out[n] = sum_k slot_out[n*8+k] ----------------
__global__ __launch_bounds__(256) void gather_kern(
    const float* __restrict__ so, float* __restrict__ out) {
  const int n = blockIdx.x;
  const int c = threadIdx.x * 4;
  float4 a = make_float4(0.f, 0.f, 0.f, 0.f);
#pragma unroll
  for (int k = 0; k < TOPK; ++k) {
    const float4 v = *(const float4*)&so[((size_t)(n * TOPK + k)) * HDIM + c];
    a.x += v.x; a.y += v.y; a.z += v.z; a.w += v.w;
  }
  *(float4*)&out[(size_t)n * HDIM + c] = a;
}

extern "C" void kernel_launch(void* const* d_in, const int* in_sizes, int n_in,
                              void* d_out, int out_size, void* d_ws, size_t ws_size,
                              hipStream_t stream) {
  const float* x   = (const float*)d_in[0];
  const float* gw  = (const float*)d_in[1];
  const float* gup = (const float*)d_in[2];
  const float* dwn = (const float*)d_in[3];
  float* out = (float*)d_out;

  char* ws = (char*)d_ws;
  // ws is 768 MiB (harness poison fill = 786432 KB). Layout (260.5 MiB used):
  // cnt 1KB | slot_tok 128KB | slot_w 128KB | pad | xb 4MB | hbuf 48MB | gupb 96MB | dwnb 48MB | slot_out 64MB
  int*   cnt      = (int*)(ws + 0);
  int*   slot_tok = (int*)(ws + 1024);
  float* slot_w   = (float*)(ws + 1024 + 131072);
  short* xb       = (short*)(ws + 524288);
  short* hbuf     = (short*)(ws + 4718592);       // 524288 + 4 MiB
  short* gupb     = (short*)(ws + 55050240);      // hbuf + 48 MiB
  short* dwnb     = (short*)(ws + 155713536);     // gupb + 96 MiB
  float* slot_out = (float*)(ws + 206045184);     // dwnb + 48 MiB; end = 273154048

  hipMemsetAsync(cnt, 0, 1024, stream);
  router_kern<<<NTOK / 8, 256, 0, stream>>>(x, gw, cnt, slot_tok, slot_w, xb);
  cvt_kern<<<CVT_GRID, 256, 0, stream>>>(gup, dwn, gupb, dwnb);
  gemm1_kern<<<3072, 256, 0, stream>>>(xb, gupb, cnt, slot_tok, hbuf);
  gemm2_kern<<<2048, 256, 0, stream>>>(hbuf, dwnb, cnt, slot_tok, slot_w, slot_out);
  gather_kern<<<NTOK, 256, 0, stream>>>(slot_out, out);
}

// Round 9
// 562.440 us; speedup vs baseline: 1.0747x; 1.0747x over previous
//
#include <hip/hip_runtime.h>
#include <stdint.h>
#include <math.h>

#define NTOK  2048
#define HDIM  1024
#define FDIM  768
#define NEXP  32
#define TOPK  8
#define CAP   1024

typedef __attribute__((ext_vector_type(8))) short short8;
typedef __attribute__((ext_vector_type(4))) float f32x4;

__device__ __forceinline__ short f2bf(float f) {
  union { float f; uint32_t u; } c; c.f = f;
  uint32_t u = c.u;
  u += 0x7fffu + ((u >> 16) & 1u);   // RNE
  return (short)(u >> 16);
}

__device__ __forceinline__ short8 pack8(float4 a, float4 b) {
  short8 r;
  r[0] = f2bf(a.x); r[1] = f2bf(a.y); r[2] = f2bf(a.z); r[3] = f2bf(a.w);
  r[4] = f2bf(b.x); r[5] = f2bf(b.y); r[6] = f2bf(b.z); r[7] = f2bf(b.w);
  return r;
}

// async global->LDS, 16B per lane; LDS dest must be wave-uniform (HW adds lane*16B)
__device__ __forceinline__ void gload16(const short* g, short* l) {
  __builtin_amdgcn_global_load_lds(
      (__attribute__((address_space(1))) uint32_t*)g,
      (__attribute__((address_space(3))) uint32_t*)l, 16, 0, 0);
}

// ---------------- router: logits (fp32), top-8, renorm weights, scatter, x->bf16 ----------------
__global__ __launch_bounds__(256) void router_kern(
    const float* __restrict__ x, const float* __restrict__ gw,
    int* __restrict__ cnt, int* __restrict__ slot_tok,
    float* __restrict__ slot_w, short* __restrict__ xb) {
  const int n0 = blockIdx.x * 8;      // 8 tokens per block, grid = 256
  const int t  = threadIdx.x;
  __shared__ float ls[8][32];

  const int e = t >> 3;
  const int j = t & 7;
  float acc[8];
#pragma unroll
  for (int i = 0; i < 8; ++i) acc[i] = 0.f;
  const float* gwe = gw + (size_t)e * HDIM;
  for (int i = 0; i < 128; ++i) {
    const int k = j + 8 * i;
    const float gv = gwe[k];
#pragma unroll
    for (int tok = 0; tok < 8; ++tok)
      acc[tok] += gv * x[(size_t)(n0 + tok) * HDIM + k];
  }
#pragma unroll
  for (int tok = 0; tok < 8; ++tok) {
    float v = acc[tok];
    v += __shfl_xor(v, 1); v += __shfl_xor(v, 2); v += __shfl_xor(v, 4);
    if (j == 0) ls[tok][e] = v;
  }
  __syncthreads();

  if (t < 8) {
    const int n = n0 + t;
    float lv[32];
#pragma unroll
    for (int i = 0; i < 32; ++i) lv[i] = ls[t][i];
    int   idx[TOPK];
    float val[TOPK];
    for (int kk = 0; kk < TOPK; ++kk) {
      float best = -INFINITY; int bi = 0;
      for (int i = 0; i < 32; ++i)
        if (lv[i] > best) { best = lv[i]; bi = i; }   // strict > : first-index tie-break
      val[kk] = best; idx[kk] = bi; lv[bi] = -INFINITY;
    }
    const float m = val[0];
    float w[TOPK]; float wsum = 0.f;
    for (int kk = 0; kk < TOPK; ++kk) { w[kk] = __expf(val[kk] - m); wsum += w[kk]; }
    const float inv = 1.f / wsum;
    for (int kk = 0; kk < TOPK; ++kk) {
      const int ee = idx[kk];
      const int pos = atomicAdd(&cnt[ee], 1);
      if (pos < CAP) {
        slot_tok[ee * CAP + pos] = n * TOPK + kk;
        slot_w[ee * CAP + pos]   = w[kk] * inv;
      }
    }
  }

  const size_t base = (size_t)n0 * HDIM;
  for (int i = t; i < 8 * HDIM; i += 256)
    xb[base + i] = f2bf(x[base + i]);
}

// ---------------- GEMM1: h = silu(x@Wg^T)*(x@Wu^T); 128m x 64f; fused fp32->bf16 B-staging ----------------
// XCD-affinity: 1-D grid 3072, linear_id % 8 == e % 8 -> expert's blocks co-resident on one XCD;
// they stream kb in loose lockstep so the fp32 panel's live kb-slice (<1 MB) stays L2-resident.
// Per K-step: STAGE_LOAD (A gload16 x2 + B fp32 float4 x4 to regs) BEFORE COMPUTE (latency hides
// under MFMA); pack8 + ds_write_b128 AFTER COMPUTE publishes B into the next buffer.
__global__ __launch_bounds__(256) void gemm1_kern(
    const short* __restrict__ xb, const float* __restrict__ gup,
    const int* __restrict__ cnt, const int* __restrict__ slot_tok,
    short* __restrict__ hbuf) {
  const int id  = blockIdx.x;
  const int xcd = id & 7;
  const int idx = id >> 3;            // 0..383
  const int e   = xcd + 8 * (idx / 96);
  const int w96 = idx % 96;
  const int f0  = (w96 % 12) * 64;
  const int r0  = (w96 / 12) * 128;

  const int mcnt = min(cnt[e], CAP);
  if (r0 >= mcnt) return;

  __shared__ short As[2][128 * 32];   // 2 x 8 KB
  __shared__ short Bg[2][64 * 32];    // 2 x 4 KB
  __shared__ short Bu[2][64 * 32];    // 2 x 4 KB  -> 32 KB total

  const int t = threadIdx.x;
  const int wave = t >> 6, lane = t & 63;

  // A staging: 2 granules/thread over [128 rows][4 segs]; per-lane gathered source
  const int la0 = wave * 128 + lane;
  const int la1 = la0 + 64;
  const int arow0 = la0 >> 2, aseg0 = la0 & 3;
  const int arow1 = la1 >> 2, aseg1 = la1 & 3;
  int tok0 = 0, tok1 = 0;
  if (r0 + arow0 < mcnt) tok0 = slot_tok[e * CAP + r0 + arow0] >> 3;
  if (r0 + arow1 < mcnt) tok1 = slot_tok[e * CAP + r0 + arow1] >> 3;
  const short* aSrc0 = xb + (size_t)tok0 * HDIM + aseg0 * 8;
  const short* aSrc1 = xb + (size_t)tok1 * HDIM + aseg1 * 8;

  // B staging: granule t over [64 rows][4 segs]; fp32 source, bf16 dest = Bg/Bu[b][t*8]
  const int brow = t >> 2, bseg = t & 3;
  const float* gSrcF = gup + ((size_t)(e * 1536 + f0 + brow)) * HDIM + bseg * 8;
  const float* uSrcF = gup + ((size_t)(e * 1536 + 768 + f0 + brow)) * HDIM + bseg * 8;

  const int wm = (wave & 1) * 64, wf = (wave >> 1) * 32;
  const int lrow = lane & 15, lk = (lane >> 4) * 8;

  f32x4 accg[4][2], accu[4][2];
#pragma unroll
  for (int a = 0; a < 4; ++a)
#pragma unroll
    for (int b = 0; b < 2; ++b) {
      accg[a][b] = (f32x4){0.f, 0.f, 0.f, 0.f};
      accu[a][b] = (f32x4){0.f, 0.f, 0.f, 0.f};
    }

  float4 g0, g1, u0, u1;              // staged fp32 B (in flight across COMPUTE)

  auto STAGE_LOAD = [&](int b, int kb) {
    gload16(aSrc0 + kb, &As[b][wave * 1024]);
    gload16(aSrc1 + kb, &As[b][wave * 1024 + 512]);
    g0 = *(const float4*)(gSrcF + kb);
    g1 = *(const float4*)(gSrcF + kb + 4);
    u0 = *(const float4*)(uSrcF + kb);
    u1 = *(const float4*)(uSrcF + kb + 4);
  };

  auto STAGE_WRITE = [&](int b) {
    *(short8*)&Bg[b][t * 8] = pack8(g0, g1);
    *(short8*)&Bu[b][t * 8] = pack8(u0, u1);
  };

  auto COMPUTE = [&](int b) {
    short8 af[4], bg[2], bu[2];
#pragma unroll
    for (int mt = 0; mt < 4; ++mt)
      af[mt] = *(const short8*)&As[b][(wm + mt * 16 + lrow) * 32 + lk];
#pragma unroll
    for (int nt = 0; nt < 2; ++nt) {
      bg[nt] = *(const short8*)&Bg[b][(wf + nt * 16 + lrow) * 32 + lk];
      bu[nt] = *(const short8*)&Bu[b][(wf + nt * 16 + lrow) * 32 + lk];
    }
#pragma unroll
    for (int mt = 0; mt < 4; ++mt)
#pragma unroll
      for (int nt = 0; nt < 2; ++nt) {
        accg[mt][nt] = __builtin_amdgcn_mfma_f32_16x16x32_bf16(af[mt], bg[nt], accg[mt][nt], 0, 0, 0);
        accu[mt][nt] = __builtin_amdgcn_mfma_f32_16x16x32_bf16(af[mt], bu[nt], accu[mt][nt], 0, 0, 0);
      }
  };

  STAGE_LOAD(0, 0);
  STAGE_WRITE(0);
  __syncthreads();                    // drains A gloads + B ds_writes: tile 0 resident
  int cur = 0;
  for (int kb = 32; kb < HDIM; kb += 32) {
    STAGE_LOAD(cur ^ 1, kb);          // next tile's loads fly under COMPUTE
    COMPUTE(cur);
    STAGE_WRITE(cur ^ 1);             // convert + publish next B
    __syncthreads();
    cur ^= 1;
  }
  COMPUTE(cur);

  // epilogue: silu(g)*u -> bf16 h[e][pos][f]   (mapping HW-verified rounds 0-3,6,7)
#pragma unroll
  for (int mt = 0; mt < 4; ++mt)
#pragma unroll
    for (int rr = 0; rr < 4; ++rr) {
      const int pos = r0 + wm + mt * 16 + (lane >> 4) * 4 + rr;
      if (pos < mcnt) {
#pragma unroll
        for (int nt = 0; nt < 2; ++nt) {
          const float g = accg[mt][nt][rr];
          const float u = accu[mt][nt][rr];
          const float hv = (g / (1.f + __expf(-g))) * u;
          hbuf[((size_t)e * CAP + pos) * FDIM + f0 + wf + nt * 16 + (lane & 15)] = f2bf(hv);
        }
      }
    }
}

// ---------------- GEMM2: slot_out[s] = w_s * (h @ Wd^T); 128x128; fused fp32->bf16 B-staging ----------------
// XCD-affinity: 1-D grid 2048; expert's 3 MB fp32 dwn panel L2-resident per XCD window.
__global__ __launch_bounds__(256) void gemm2_kern(
    const short* __restrict__ hbuf, const float* __restrict__ dwn,
    const int* __restrict__ cnt, const int* __restrict__ slot_tok,
    const float* __restrict__ slot_w, float* __restrict__ slot_out) {
  const int id  = blockIdx.x;
  const int xcd = id & 7;
  const int idx = id >> 3;            // 0..255
  const int e   = xcd + 8 * (idx >> 6);
  const int w64 = idx & 63;
  const int n0  = (w64 & 7) * 128;
  const int r0  = (w64 >> 3) * 128;

  const int mcnt = min(cnt[e], CAP);
  if (r0 >= mcnt) return;

  __shared__ short As[2][128 * 32];   // 2 x 8 KB
  __shared__ short Bs[2][128 * 32];   // 2 x 8 KB -> 32 KB total

  const int t = threadIdx.x;
  const int wave = t >> 6, lane = t & 63;

  // A staging (hbuf bf16, gload16): granules l0, l1 over [128 rows][4 segs]
  const int l0 = wave * 128 + lane;
  const int l1 = l0 + 64;
  const int ar0 = l0 >> 2, as0 = l0 & 3;
  const int ar1 = l1 >> 2, as1 = l1 & 3;
  const short* aSrc0 = hbuf + ((size_t)e * CAP + r0 + ar0) * FDIM + as0 * 8;
  const short* aSrc1 = hbuf + ((size_t)e * CAP + r0 + ar1) * FDIM + as1 * 8;
  // B staging (dwn fp32 -> regs -> pack -> LDS): same two granules
  const float* bSrcF0 = dwn + ((size_t)(e * HDIM + n0 + ar0)) * FDIM + as0 * 8;
  const float* bSrcF1 = dwn + ((size_t)(e * HDIM + n0 + ar1)) * FDIM + as1 * 8;

  const int wm = (wave & 1) * 64, wn = (wave >> 1) * 64;
  const int lrow = lane & 15, lk = (lane >> 4) * 8;

  f32x4 acc[4][4];
#pragma unroll
  for (int a = 0; a < 4; ++a)
#pragma unroll
    for (int b = 0; b < 4; ++b) acc[a][b] = (f32x4){0.f, 0.f, 0.f, 0.f};

  float4 b00, b01, b10, b11;

  auto STAGE_LOAD = [&](int b, int kb) {
    gload16(aSrc0 + kb, &As[b][wave * 1024]);
    gload16(aSrc1 + kb, &As[b][wave * 1024 + 512]);
    b00 = *(const float4*)(bSrcF0 + kb);
    b01 = *(const float4*)(bSrcF0 + kb + 4);
    b10 = *(const float4*)(bSrcF1 + kb);
    b11 = *(const float4*)(bSrcF1 + kb + 4);
  };

  auto STAGE_WRITE = [&](int b) {
    *(short8*)&Bs[b][l0 * 8] = pack8(b00, b01);
    *(short8*)&Bs[b][l1 * 8] = pack8(b10, b11);
  };

  auto COMPUTE = [&](int b) {
    short8 af[4], bf[4];
#pragma unroll
    for (int i = 0; i < 4; ++i) {
      af[i] = *(const short8*)&As[b][(wm + i * 16 + lrow) * 32 + lk];
      bf[i] = *(const short8*)&Bs[b][(wn + i * 16 + lrow) * 32 + lk];
    }
#pragma unroll
    for (int mt = 0; mt < 4; ++mt)
#pragma unroll
      for (int nt = 0; nt < 4; ++nt)
        acc[mt][nt] = __builtin_amdgcn_mfma_f32_16x16x32_bf16(af[mt], bf[nt], acc[mt][nt], 0, 0, 0);
  };

  STAGE_LOAD(0, 0);
  STAGE_WRITE(0);
  __syncthreads();
  int cur = 0;
  for (int kb = 32; kb < FDIM; kb += 32) {
    STAGE_LOAD(cur ^ 1, kb);
    COMPUTE(cur);
    STAGE_WRITE(cur ^ 1);
    __syncthreads();
    cur ^= 1;
  }
  COMPUTE(cur);

  // epilogue: weighted write to slot_out (mapping HW-verified rounds 0-3,6,7)
#pragma unroll
  for (int mt = 0; mt < 4; ++mt)
#pragma unroll
    for (int rr = 0; rr < 4; ++rr) {
      const int pos = r0 + wm + mt * 16 + (lane >> 4) * 4 + rr;
      if (pos < mcnt) {
        const int s = slot_tok[e * CAP + pos];
        const float w = slot_w[e * CAP + pos];
#pragma unroll
        for (int nt = 0; nt < 4; ++nt)
          slot_out[(size_t)s * HDIM + n0 + wn + nt * 16 + (lane & 15)] = w * acc[mt][nt][rr];
      }
    }
}

// ---------------- gather: out[n] = sum_k slot_out[n*8+k] ----------------
__global__ __launch_bounds__(256) void gather_kern(
    const float* __restrict__ so, float* __restrict__ out) {
  const int n = blockIdx.x;
  const int c = threadIdx.x * 4;
  float4 a = make_float4(0.f, 0.f, 0.f, 0.f);
#pragma unroll
  for (int k = 0; k < TOPK; ++k) {
    const float4 v = *(const float4*)&so[((size_t)(n * TOPK + k)) * HDIM + c];
    a.x += v.x; a.y += v.y; a.z += v.z; a.w += v.w;
  }
  *(float4*)&out[(size_t)n * HDIM + c] = a;
}

extern "C" void kernel_launch(void* const* d_in, const int* in_sizes, int n_in,
                              void* d_out, int out_size, void* d_ws, size_t ws_size,
                              hipStream_t stream) {
  const float* x   = (const float*)d_in[0];
  const float* gw  = (const float*)d_in[1];
  const float* gup = (const float*)d_in[2];
  const float* dwn = (const float*)d_in[3];
  float* out = (float*)d_out;

  char* ws = (char*)d_ws;
  // Layout (116.5 MiB used): cnt 1KB | slot_tok 128KB | slot_w 128KB | pad | xb 4MB | hbuf 48MB | slot_out 64MB
  int*   cnt      = (int*)(ws + 0);
  int*   slot_tok = (int*)(ws + 1024);
  float* slot_w   = (float*)(ws + 1024 + 131072);
  short* xb       = (short*)(ws + 524288);
  short* hbuf     = (short*)(ws + 4718592);       // 524288 + 4 MiB
  float* slot_out = (float*)(ws + 55050240);      // hbuf + 48 MiB; end = 122161152

  hipMemsetAsync(cnt, 0, 1024, stream);
  router_kern<<<NTOK / 8, 256, 0, stream>>>(x, gw, cnt, slot_tok, slot_w, xb);
  gemm1_kern<<<3072, 256, 0, stream>>>(xb, gup, cnt, slot_tok, hbuf);
  gemm2_kern<<<2048, 256, 0, stream>>>(hbuf, dwn, cnt, slot_tok, slot_w, slot_out);
  gather_kern<<<NTOK, 256, 0, stream>>>(slot_out, out);
}